// Round 1
// baseline (991.084 us; speedup 1.0000x reference)
//
#include <hip/hip_runtime.h>

// ---------------------------------------------------------------------------
// Recommender decoder: 4x Bahdanau attention -> LSTM cell -> vocab softmax
// All matmuls via bf16 MFMA (16x16x32), fp32 accumulate.
// ---------------------------------------------------------------------------

typedef __bf16 bf16;
typedef __bf16 bf16x8 __attribute__((ext_vector_type(8)));
typedef __bf16 bf16x4 __attribute__((ext_vector_type(4)));
typedef float f32x4 __attribute__((ext_vector_type(4)));

struct Seg3A { const bf16* p[3]; unsigned mask[3]; };
struct Seg3B { const void* p[3]; };

__device__ __forceinline__ float fast_tanh(float x) {
    float xc = fminf(fmaxf(x, -15.f), 15.f);
    float e = __expf(2.f * xc);
    return (e - 1.f) / (e + 1.f);
}
__device__ __forceinline__ float fast_sigmoid(float x) {
    return 1.f / (1.f + __expf(-x));
}

// ---------------------------------------------------------------------------
// fp32 -> bf16 elementwise convert (vectorized, n multiple of 4)
// ---------------------------------------------------------------------------
__global__ __launch_bounds__(256) void conv_kernel(const float* __restrict__ in,
                                                   bf16* __restrict__ out, int n4) {
    int i = blockIdx.x * 256 + threadIdx.x;
    if (i < n4) {
        f32x4 v = *(const f32x4*)(in + (size_t)i * 4);
        bf16x4 w;
        w[0] = (bf16)v[0]; w[1] = (bf16)v[1]; w[2] = (bf16)v[2]; w[3] = (bf16)v[3];
        *(bf16x4*)(out + (size_t)i * 4) = w;
    }
}

// ---------------------------------------------------------------------------
// fp32 (R,C) -> bf16 (C,R) transpose-convert. R,C multiples of 32.
// block (32,8), grid (C/32, R/32)
// ---------------------------------------------------------------------------
__global__ __launch_bounds__(256) void transpose_conv_kernel(const float* __restrict__ in,
                                                             bf16* __restrict__ out,
                                                             int R, int C) {
    __shared__ float tile[32][33];
    int tx = threadIdx.x, ty = threadIdx.y;
    int c0 = blockIdx.x * 32;
    int r0 = blockIdx.y * 32;
#pragma unroll
    for (int i = 0; i < 4; ++i) {
        int r = r0 + ty + i * 8;
        tile[ty + i * 8][tx] = in[(size_t)r * C + c0 + tx];
    }
    __syncthreads();
#pragma unroll
    for (int i = 0; i < 4; ++i) {
        int c = c0 + ty + i * 8;
        out[(size_t)c * R + r0 + tx] = (bf16)tile[tx][ty + i * 8];
    }
}

// ---------------------------------------------------------------------------
// GEMM: C[M,N] = act(A @ B^T + bias1 (+bias2))
//  A: bf16, segmented along K (segments of 1024, each seg: ptr + (m&mask)*1024)
//  B: bf16 (N,K layout, per-seg ptr, common row stride) or fp32 converted on-fly
//  256 threads = 4 waves (2x2), tile BM x BN, BK=64, XOR-swizzled LDS.
// ---------------------------------------------------------------------------
template <int BM, int BN, bool B_F32, bool OUT_BF16, bool DO_TANH>
__global__ __launch_bounds__(256) void gemm_kernel(Seg3A sa, Seg3B sb, int bstride,
                                                   const float* __restrict__ bias1,
                                                   const float* __restrict__ bias2,
                                                   void* __restrict__ Cout, int N, int K) {
    constexpr int BK = 64;
    constexpr int FM = BM / 32, FN = BN / 32;
    __shared__ bf16 As[BM * BK];
    __shared__ bf16 Bs[BN * BK];
    char* Asb = (char*)As;
    char* Bsb = (char*)Bs;

    const int tid = threadIdx.x;
    const int lane = tid & 63;
    const int wave = tid >> 6;
    const int bm0 = blockIdx.y * BM;
    const int bn0 = blockIdx.x * BN;
    const int wm = (wave >> 1) * (BM / 2);
    const int wn = (wave & 1) * (BN / 2);

    f32x4 acc[FM][FN] = {};

    for (int k0 = 0; k0 < K; k0 += BK) {
        const int seg = k0 >> 10;
        const int kloc = k0 & 1023;
        // ---- stage A (bf16 source, 8-elt vector loads) ----
        {
            const bf16* Ap = sa.p[seg] + kloc;
            const unsigned amask = sa.mask[seg];
#pragma unroll
            for (int it = 0; it < BM / 32; ++it) {
                int id = it * 256 + tid;
                int row = id >> 3, v8 = id & 7;
                unsigned grow = (unsigned)(bm0 + row) & amask;
                bf16x8 v = *(const bf16x8*)(Ap + (size_t)grow * 1024 + v8 * 8);
                *(bf16x8*)(Asb + row * 128 + ((v8 * 16) ^ ((row & 7) << 4))) = v;
            }
        }
        // ---- stage B ----
        if (!B_F32) {
            const bf16* Bp = (const bf16*)sb.p[seg] + kloc;
#pragma unroll
            for (int it = 0; it < BN / 32; ++it) {
                int id = it * 256 + tid;
                int row = id >> 3, v8 = id & 7;
                int gn = bn0 + row;
                bf16x8 v;
                if (gn < N) {
                    v = *(const bf16x8*)(Bp + (size_t)gn * bstride + v8 * 8);
                } else {
#pragma unroll
                    for (int j = 0; j < 8; ++j) v[j] = (bf16)0.f;
                }
                *(bf16x8*)(Bsb + row * 128 + ((v8 * 16) ^ ((row & 7) << 4))) = v;
            }
        } else {
            const float* Bp = (const float*)sb.p[seg] + kloc;
#pragma unroll
            for (int it = 0; it < BN / 16; ++it) {
                int id = it * 256 + tid;
                int row = id >> 4, c4 = id & 15;
                int gn = bn0 + row;
                f32x4 v = {0.f, 0.f, 0.f, 0.f};
                if (gn < N) v = *(const f32x4*)(Bp + (size_t)gn * bstride + c4 * 4);
                bf16x4 w;
                w[0] = (bf16)v[0]; w[1] = (bf16)v[1]; w[2] = (bf16)v[2]; w[3] = (bf16)v[3];
                *(bf16x4*)(Bsb + row * 128 + ((c4 * 8) ^ ((row & 7) << 4))) = w;
            }
        }
        __syncthreads();
#pragma unroll
        for (int ks = 0; ks < 2; ++ks) {
            bf16x8 af[FM], bfr[FN];
            const int kk = ks * 64 + ((lane >> 4) * 16);  // byte offset of 8 k-elems
#pragma unroll
            for (int fm = 0; fm < FM; ++fm) {
                int row = wm + fm * 16 + (lane & 15);
                af[fm] = *(const bf16x8*)(Asb + row * 128 + (kk ^ ((row & 7) << 4)));
            }
#pragma unroll
            for (int fn = 0; fn < FN; ++fn) {
                int row = wn + fn * 16 + (lane & 15);
                bfr[fn] = *(const bf16x8*)(Bsb + row * 128 + (kk ^ ((row & 7) << 4)));
            }
#pragma unroll
            for (int fm = 0; fm < FM; ++fm)
#pragma unroll
                for (int fn = 0; fn < FN; ++fn)
                    acc[fm][fn] = __builtin_amdgcn_mfma_f32_16x16x32_bf16(
                        af[fm], bfr[fn], acc[fm][fn], 0, 0, 0);
        }
        __syncthreads();
    }

    // epilogue: bias + optional tanh; C/D layout col=lane&15, row=(lane>>4)*4+j
    const int crow = (lane >> 4) * 4;
    const int ccol = lane & 15;
#pragma unroll
    for (int fm = 0; fm < FM; ++fm) {
#pragma unroll
        for (int fn = 0; fn < FN; ++fn) {
            int gn = bn0 + wn + fn * 16 + ccol;
            if (gn >= N) continue;
            float bv = bias1 ? bias1[gn] : 0.f;
            if (bias2) bv += bias2[gn];
#pragma unroll
            for (int j = 0; j < 4; ++j) {
                int gm = bm0 + wm + fm * 16 + crow + j;
                float val = acc[fm][fn][j] + bv;
                if (DO_TANH) val = fast_tanh(val);
                if (OUT_BF16)
                    ((bf16*)Cout)[(size_t)gm * N + gn] = (bf16)val;
                else
                    ((float*)Cout)[(size_t)gm * N + gn] = val;
            }
        }
    }
}

// ---------------------------------------------------------------------------
// Attention finish: e[s] = dot(t[s*64+b,:], V) + bv ; softmax over s ;
// ctx[b,:] = sum_s alpha[s] * values[s,b,:]   (ctx written bf16)
// block = b (64 blocks), 256 threads.
// ---------------------------------------------------------------------------
__global__ __launch_bounds__(256) void attn_score_ctx_kernel(
    const bf16* __restrict__ t, const float* __restrict__ V,
    const float* __restrict__ bv, const float* __restrict__ values,
    bf16* __restrict__ ctx, int S) {
    __shared__ float e_sm[128];
    const int b = blockIdx.x;
    const int tid = threadIdx.x;
    const int lane = tid & 63, wave = tid >> 6;

    for (int s = wave; s < S; s += 4) {
        const bf16* row = t + ((size_t)s * 64 + b) * 1024 + lane * 16;
        bf16x8 v0 = *(const bf16x8*)(row);
        bf16x8 v1 = *(const bf16x8*)(row + 8);
        const float* vp = V + lane * 16;
        float sum = 0.f;
#pragma unroll
        for (int j = 0; j < 8; ++j) sum += (float)v0[j] * vp[j] + (float)v1[j] * vp[8 + j];
#pragma unroll
        for (int off = 32; off >= 1; off >>= 1) sum += __shfl_xor(sum, off);
        if (lane == 0) e_sm[s] = sum + bv[0];
    }
    __syncthreads();
    if (wave == 0) {
        float m = -1e30f;
        for (int s = lane; s < S; s += 64) m = fmaxf(m, e_sm[s]);
#pragma unroll
        for (int off = 32; off >= 1; off >>= 1) m = fmaxf(m, __shfl_xor(m, off));
        float sum = 0.f;
        for (int s = lane; s < S; s += 64) {
            float p = __expf(e_sm[s] - m);
            e_sm[s] = p;
            sum += p;
        }
#pragma unroll
        for (int off = 32; off >= 1; off >>= 1) sum += __shfl_xor(sum, off);
        float inv = 1.f / sum;
        for (int s = lane; s < S; s += 64) e_sm[s] *= inv;
    }
    __syncthreads();
    float acc0 = 0.f, acc1 = 0.f, acc2 = 0.f, acc3 = 0.f;
    for (int s = 0; s < S; ++s) {
        float a = e_sm[s];
        const float* vrow = values + ((size_t)s * 64 + b) * 1024;
        acc0 += a * vrow[tid];
        acc1 += a * vrow[tid + 256];
        acc2 += a * vrow[tid + 512];
        acc3 += a * vrow[tid + 768];
    }
    bf16* c = ctx + (size_t)b * 1024;
    c[tid] = (bf16)acc0;
    c[tid + 256] = (bf16)acc1;
    c[tid + 512] = (bf16)acc2;
    c[tid + 768] = (bf16)acc3;
}

// ---------------------------------------------------------------------------
// LSTM cell elementwise (gate order i,f,g,o). 65536 threads.
// ---------------------------------------------------------------------------
__global__ __launch_bounds__(256) void lstm_kernel(const float* __restrict__ gates,
                                                   const float* __restrict__ c0,
                                                   float* __restrict__ h_out,
                                                   float* __restrict__ c_out,
                                                   bf16* __restrict__ h_b) {
    int idx = blockIdx.x * 256 + threadIdx.x;
    int b = idx >> 10, hh = idx & 1023;
    const float* g = gates + (size_t)b * 4096;
    float gi = g[hh], gf = g[1024 + hh], gg = g[2048 + hh], go = g[3072 + hh];
    float c = fast_sigmoid(gf) * c0[idx] + fast_sigmoid(gi) * fast_tanh(gg);
    float h = fast_sigmoid(go) * fast_tanh(c);
    h_out[idx] = h;
    c_out[idx] = c;
    h_b[idx] = (bf16)h;
}

// ---------------------------------------------------------------------------
// Row softmax over N=50000, block per row (1024 threads).
// ---------------------------------------------------------------------------
__global__ __launch_bounds__(1024) void softmax_kernel(const float* __restrict__ in,
                                                       float* __restrict__ out, int N) {
    const int row = blockIdx.x;
    const float* x = in + (size_t)row * N;
    float* y = out + (size_t)row * N;
    __shared__ float r1[16], r2[16];
    const int tid = threadIdx.x, lane = tid & 63, w = tid >> 6;

    float m = -1e30f;
    for (int i = tid; i < N; i += 1024) m = fmaxf(m, x[i]);
#pragma unroll
    for (int off = 32; off >= 1; off >>= 1) m = fmaxf(m, __shfl_xor(m, off));
    if (lane == 0) r1[w] = m;
    __syncthreads();
    float bm = -1e30f;
#pragma unroll
    for (int j = 0; j < 16; ++j) bm = fmaxf(bm, r1[j]);

    float s = 0.f;
    for (int i = tid; i < N; i += 1024) s += __expf(x[i] - bm);
#pragma unroll
    for (int off = 32; off >= 1; off >>= 1) s += __shfl_xor(s, off);
    if (lane == 0) r2[w] = s;
    __syncthreads();
    float bs = 0.f;
#pragma unroll
    for (int j = 0; j < 16; ++j) bs += r2[j];
    float inv = 1.f / bs;
    for (int i = tid; i < N; i += 1024) y[i] = __expf(x[i] - bm) * inv;
}

// ---------------------------------------------------------------------------
// Host launcher
// ---------------------------------------------------------------------------
extern "C" void kernel_launch(void* const* d_in, const int* in_sizes, int n_in,
                              void* d_out, int out_size, void* d_ws, size_t ws_size,
                              hipStream_t stream) {
    // input pointers (setup_inputs order)
    const float* Xu = (const float*)d_in[0];    // (50,64,1024)
    const float* Xn = (const float*)d_in[2];    // (50,64,1024)
    const float* Xp = (const float*)d_in[4];    // (100,64,1024)
    const float* h0 = (const float*)d_in[6];    // (1,64,1024)
    const float* c0 = (const float*)d_in[7];    // (1,64,1024)
    const float* Xd = (const float*)d_in[8];    // (20,64,1024)
    const float* W_user = (const float*)d_in[9];
    const float* b_user = (const float*)d_in[10];
    const float* V_user = (const float*)d_in[11];
    const float* bv_user = (const float*)d_in[12];
    const float* W_neigh = (const float*)d_in[13];
    const float* b_neigh = (const float*)d_in[14];
    const float* V_neigh = (const float*)d_in[15];
    const float* bv_neigh = (const float*)d_in[16];
    const float* W_over = (const float*)d_in[17];
    const float* b_over = (const float*)d_in[18];
    const float* V_over = (const float*)d_in[19];
    const float* bv_over = (const float*)d_in[20];
    const float* W_comb = (const float*)d_in[21];
    const float* b_comb = (const float*)d_in[22];
    const float* V_comb = (const float*)d_in[23];
    const float* bv_comb = (const float*)d_in[24];
    const float* W_ih = (const float*)d_in[25];
    const float* W_hh = (const float*)d_in[26];
    const float* b_ih = (const float*)d_in[27];
    const float* b_hh = (const float*)d_in[28];
    const float* W_out = (const float*)d_in[29];
    const float* b_out = (const float*)d_in[30];

    float* out_act = (float*)d_out;                 // (1,64,50000)
    float* out_h = out_act + (size_t)64 * 50000;    // (1,64,1024)
    float* out_c = out_h + (size_t)64 * 1024;       // (1,64,1024)

    // workspace layout (bump allocator, 256B aligned)
    char* ws = (char*)d_ws;
    size_t off = 0;
    auto alloc = [&](size_t bytes) -> char* {
        char* p = ws + off;
        off += (bytes + 255) & ~(size_t)255;
        return p;
    };
    bf16* Xu_b = (bf16*)alloc((size_t)3200 * 1024 * 2);
    bf16* Xn_b = (bf16*)alloc((size_t)3200 * 1024 * 2);
    bf16* Xp_b = (bf16*)alloc((size_t)6400 * 1024 * 2);
    bf16* Xd_b = (bf16*)alloc((size_t)1280 * 1024 * 2);
    bf16* h0_b = (bf16*)alloc((size_t)64 * 1024 * 2);
    bf16* Wt_u = (bf16*)alloc((size_t)1024 * 1024 * 2);
    bf16* Wt_n = (bf16*)alloc((size_t)1024 * 1024 * 2);
    bf16* Wt_o = (bf16*)alloc((size_t)1024 * 3072 * 2);
    bf16* Wt_c = (bf16*)alloc((size_t)1024 * 2048 * 2);
    bf16* t_buf = (bf16*)alloc((size_t)6400 * 1024 * 2);  // shared by all 4 attns
    bf16* ctx_u = (bf16*)alloc((size_t)64 * 1024 * 2);
    bf16* ctx_n = (bf16*)alloc((size_t)64 * 1024 * 2);
    bf16* ctx_o = (bf16*)alloc((size_t)64 * 1024 * 2);
    bf16* ctx_c = (bf16*)alloc((size_t)64 * 1024 * 2);
    float* gates = (float*)alloc((size_t)64 * 4096 * 4);
    bf16* h_b = (bf16*)alloc((size_t)64 * 1024 * 2);
    // logits aliases Xu_b/Xn_b (dead by classify time): 13.1MB >= 12.8MB
    float* logits = (float*)Xu_b;

    const unsigned FULL = ~0u;

    // ---- prep: converts ----
    conv_kernel<<<3200, 256, 0, stream>>>(Xu, Xu_b, 3200 * 1024 / 4);
    conv_kernel<<<3200, 256, 0, stream>>>(Xn, Xn_b, 3200 * 1024 / 4);
    conv_kernel<<<6400, 256, 0, stream>>>(Xp, Xp_b, 6400 * 1024 / 4);
    conv_kernel<<<1280, 256, 0, stream>>>(Xd, Xd_b, 1280 * 1024 / 4);
    conv_kernel<<<64, 256, 0, stream>>>(h0, h0_b, 64 * 1024 / 4);
    // ---- prep: W transposes (K,N)->(N,K) bf16 ----
    dim3 tb(32, 8);
    transpose_conv_kernel<<<dim3(32, 32), tb, 0, stream>>>(W_user, Wt_u, 1024, 1024);
    transpose_conv_kernel<<<dim3(32, 32), tb, 0, stream>>>(W_neigh, Wt_n, 1024, 1024);
    transpose_conv_kernel<<<dim3(32, 96), tb, 0, stream>>>(W_over, Wt_o, 3072, 1024);
    transpose_conv_kernel<<<dim3(32, 64), tb, 0, stream>>>(W_comb, Wt_c, 2048, 1024);

    // ---- user attention ----
    {
        Seg3A sa = {{Xu_b, Xu_b, Xu_b}, {FULL, FULL, FULL}};
        Seg3B sb = {{Wt_u, Wt_u, Wt_u}};
        gemm_kernel<128, 128, false, true, true><<<dim3(8, 25), 256, 0, stream>>>(
            sa, sb, 1024, b_user, nullptr, t_buf, 1024, 1024);
        attn_score_ctx_kernel<<<64, 256, 0, stream>>>(t_buf, V_user, bv_user, Xu, ctx_u, 50);
    }
    // ---- neighbourhood attention ----
    {
        Seg3A sa = {{Xn_b, Xn_b, Xn_b}, {FULL, FULL, FULL}};
        Seg3B sb = {{Wt_n, Wt_n, Wt_n}};
        gemm_kernel<128, 128, false, true, true><<<dim3(8, 25), 256, 0, stream>>>(
            sa, sb, 1024, b_neigh, nullptr, t_buf, 1024, 1024);
        attn_score_ctx_kernel<<<64, 256, 0, stream>>>(t_buf, V_neigh, bv_neigh, Xn, ctx_n, 50);
    }
    // ---- overall attention: feats = [product, user_ctx(bcast), neigh_ctx(bcast)] ----
    {
        Seg3A sa = {{Xp_b, ctx_u, ctx_n}, {FULL, 63u, 63u}};
        Seg3B sb = {{Wt_o, Wt_o + 1024, Wt_o + 2048}};
        gemm_kernel<128, 128, false, true, true><<<dim3(8, 50), 256, 0, stream>>>(
            sa, sb, 3072, b_over, nullptr, t_buf, 1024, 3072);
        attn_score_ctx_kernel<<<64, 256, 0, stream>>>(t_buf, V_over, bv_over, Xp, ctx_o, 100);
    }
    // ---- combine attention: feats = [overall_ctx(bcast), decoder_inputs] ----
    {
        Seg3A sa = {{ctx_o, Xd_b, Xd_b}, {63u, FULL, FULL}};
        Seg3B sb = {{Wt_c, Wt_c + 1024, Wt_c + 1024}};
        gemm_kernel<128, 128, false, true, true><<<dim3(8, 10), 256, 0, stream>>>(
            sa, sb, 2048, b_comb, nullptr, t_buf, 1024, 2048);
        attn_score_ctx_kernel<<<64, 256, 0, stream>>>(t_buf, V_comb, bv_comb, Xd, ctx_c, 20);
    }
    // ---- LSTM gates: [x | h0] @ [W_ih | W_hh]^T + b_ih + b_hh ----
    {
        Seg3A sa = {{ctx_c, h0_b, h0_b}, {FULL, FULL, FULL}};
        Seg3B sb = {{W_ih, W_hh, W_hh}};
        gemm_kernel<64, 128, true, false, false><<<dim3(32, 1), 256, 0, stream>>>(
            sa, sb, 1024, b_ih, b_hh, gates, 4096, 2048);
    }
    lstm_kernel<<<256, 256, 0, stream>>>(gates, c0, out_h, out_c, h_b);
    // ---- classify: h @ W_out^T + b_out (W_out fp32 on-the-fly) ----
    {
        Seg3A sa = {{h_b, h_b, h_b}, {FULL, FULL, FULL}};
        Seg3B sb = {{W_out, W_out, W_out}};
        gemm_kernel<64, 128, true, false, false><<<dim3((50000 + 127) / 128, 1), 256, 0, stream>>>(
            sa, sb, 1024, b_out, nullptr, logits, 50000, 1024);
    }
    softmax_kernel<<<64, 1024, 0, stream>>>(logits, out_act, 50000);
    (void)in_sizes; (void)n_in; (void)out_size; (void)ws_size;
}